// Round 1
// baseline (169.818 us; speedup 1.0000x reference)
//
#include <hip/hip_runtime.h>
#include <hip/hip_bf16.h>
#include <stdint.h>

typedef __attribute__((ext_vector_type(8))) short short8;
typedef __attribute__((ext_vector_type(4))) float f32x4;

#define N_SLOTS 65536
#define D_FEAT  64
#define BATCH   2048
#define BM      64               // batch rows per block
#define BK      64               // k per iteration
#define NC      32               // k-chunks (grid.y)
#define KCHUNK  (N_SLOTS / NC)   // 2048
#define NITER   (KCHUNK / BK)    // 32

// float -> bf16 bits, round-to-nearest-even (inputs finite, no NaN handling needed)
__device__ __forceinline__ unsigned short f2bf(float f) {
    unsigned int u = __builtin_bit_cast(unsigned int, f);
    u += 0x7fffu + ((u >> 16) & 1u);
    return (unsigned short)(u >> 16);
}

__global__ __launch_bounds__(256) void reading_main(
    const float* __restrict__ M,   // [N_SLOTS][D_FEAT]
    const float* __restrict__ W,   // [BATCH][N_SLOTS]
    float* __restrict__ out,       // [BATCH][D_FEAT] numerator accum (pre-zeroed)
    float* __restrict__ lrow)      // [BATCH] denominator accum (pre-zeroed)
{
    // XOR-swizzled bf16 tiles: slot(r,k) = r*64 + (k ^ ((r&7)<<3))  (ushort units)
    __shared__ __align__(16) unsigned short sA[BM * BK];      // exp(weight) tile [row][k]
    __shared__ __align__(16) unsigned short sB[D_FEAT * BK];  // memory tile transposed [d][k]

    const int t   = threadIdx.x;
    const int bm0 = blockIdx.x * BM;
    const int kc0 = blockIdx.y * KCHUNK;

    const int ln = t & 63;   // lane
    const int wv = t >> 6;   // wave 0..3

    float lsum[4] = {0.f, 0.f, 0.f, 0.f};
    f32x4 acc[4];
    #pragma unroll
    for (int td = 0; td < 4; ++td) acc[td] = f32x4{0.f, 0.f, 0.f, 0.f};

    // A-stage: flat float4 assignment, round r4 covers rows r4*16 + (t>>4)
    const int ar   = t >> 4;         // 0..15
    const int akof = (t & 15) * 4;   // k offset 0..60, float4

    for (int it = 0; it < NITER; ++it) {
        const int kbase = kc0 + it * BK;

        __syncthreads();   // previous iter's MFMA reads done before overwrite

        // ---- stage A: exp(weight) -> bf16, fully coalesced global reads
        #pragma unroll
        for (int r4 = 0; r4 < 4; ++r4) {
            const int row = r4 * 16 + ar;
            const float4 w4 = *reinterpret_cast<const float4*>(
                W + (size_t)(bm0 + row) * N_SLOTS + kbase + akof);
            const float e0 = __expf(w4.x), e1 = __expf(w4.y);
            const float e2 = __expf(w4.z), e3 = __expf(w4.w);
            lsum[r4] += (e0 + e1) + (e2 + e3);
            const unsigned long long pk =
                (unsigned long long)f2bf(e0)        | ((unsigned long long)f2bf(e1) << 16) |
                ((unsigned long long)f2bf(e2) << 32) | ((unsigned long long)f2bf(e3) << 48);
            const int idx = row * BK + (akof ^ ((row & 7) << 3));   // XOR hits bits 3..5 only
            *reinterpret_cast<unsigned long long*>(&sA[idx]) = pk;
        }

        // ---- stage B: memory [k][d] -> LDS transposed [d][k] bf16
        // lane = d (coalesced 256B/row loads), wave covers 16 k-rows
        {
            unsigned short pb[16];
            #pragma unroll
            for (int i = 0; i < 16; ++i)
                pb[i] = f2bf(M[(size_t)(kbase + wv * 16 + i) * D_FEAT + ln]);
            #pragma unroll
            for (int j = 0; j < 2; ++j) {
                const int kk  = wv * 16 + j * 8;
                const int idx = ln * BK + (kk ^ ((ln & 7) << 3));   // stays 8-aligned
                short8 s;
                #pragma unroll
                for (int e = 0; e < 8; ++e) s[e] = (short)pb[j * 8 + e];
                *reinterpret_cast<short8*>(&sB[idx]) = s;
            }
        }

        __syncthreads();

        // ---- MFMA: wave wv owns rows 16*wv..16*wv+15, all 4 d-tiles
        const int arow = 16 * wv + (ln & 15);
        const int kofr = (ln >> 4) * 8;   // same k-map used for A and B fragments
        #pragma unroll
        for (int ks = 0; ks < 2; ++ks) {
            const int ka = ks * 32 + kofr;
            const short8 a = *reinterpret_cast<const short8*>(
                &sA[arow * BK + (ka ^ ((arow & 7) << 3))]);
            #pragma unroll
            for (int td = 0; td < 4; ++td) {
                const int drow = 16 * td + (ln & 15);
                const short8 b = *reinterpret_cast<const short8*>(
                    &sB[drow * BK + (ka ^ ((drow & 7) << 3))]);
                acc[td] = __builtin_amdgcn_mfma_f32_16x16x32_bf16(a, b, acc[td], 0, 0, 0);
            }
        }
    }

    // ---- accumulate numerator tile (C/D map: col = lane&15, row = (lane>>4)*4 + reg)
    {
        const int ro = (ln >> 4) * 4;
        const int co = ln & 15;
        #pragma unroll
        for (int td = 0; td < 4; ++td) {
            #pragma unroll
            for (int q = 0; q < 4; ++q) {
                atomicAdd(&out[(size_t)(bm0 + 16 * wv + ro + q) * D_FEAT + 16 * td + co],
                          acc[td][q]);
            }
        }
    }

    // ---- denominator: reduce 16 lanes (same t>>4) per row, one atomic each
    #pragma unroll
    for (int r4 = 0; r4 < 4; ++r4) {
        float s = lsum[r4];
        #pragma unroll
        for (int m = 1; m < 16; m <<= 1) s += __shfl_xor(s, m, 64);
        if ((t & 15) == 0)
            atomicAdd(&lrow[bm0 + r4 * 16 + ar], s);
    }
}

__global__ __launch_bounds__(256) void reading_finalize(
    float* __restrict__ out, const float* __restrict__ lrow)
{
    const int i = blockIdx.x * 256 + threadIdx.x;   // BATCH*D_FEAT total
    out[i] = out[i] / lrow[i >> 6];
}

extern "C" void kernel_launch(void* const* d_in, const int* in_sizes, int n_in,
                              void* d_out, int out_size, void* d_ws, size_t ws_size,
                              hipStream_t stream) {
    const float* M = (const float*)d_in[0];   // memory [65536][64]
    const float* W = (const float*)d_in[1];   // weight [2048][65536]
    float* out  = (float*)d_out;
    float* lrow = (float*)d_ws;               // 2048 floats = 8 KB scratch

    hipMemsetAsync(d_out, 0, (size_t)BATCH * D_FEAT * sizeof(float), stream);
    hipMemsetAsync(d_ws,  0, (size_t)BATCH * sizeof(float), stream);

    dim3 grid(BATCH / BM, NC);
    reading_main<<<grid, 256, 0, stream>>>(M, W, out, lrow);
    reading_finalize<<<(BATCH * D_FEAT) / 256, 256, 0, stream>>>(out, lrow);
}